// Round 15
// baseline (251.158 us; speedup 1.0000x reference)
//
#include <hip/hip_runtime.h>
#include <math.h>

// Problem constants (fixed by reference setup_inputs)
#define L0   4448   // flux length
#define L1P  278    // after conv1(stride4,pad7)->1112 then maxpool4
#define L2   139    // after conv2(stride2,pad3) on 278
#define NQ   8
#define NL   3
#define SD   256
#define GRIDSZ 768  // 3 blocks/CU x 256 CUs (persistent K1)

// R21: persistent K1, prefetch with ZERO barrier-crossing live range (R20's
// prefetch spilled: VGPR=84, +138MB scratch traffic). Loads for pair pr+768
// are issued right after stage-1's barrier (fxb dead); stage 2 has no global
// ops, so its MFMA/LDS work covers the load latency; pack+ds_write into fxb
// right after stage 2, before the featU barrier. Old post-norm write and the
// loop-end barrier removed (hazard-traced safe).
//  K2 aec_circuit_kernel: unchanged (wave=sample, R13-verified).
//  Fallback (ws too small): R16 fused kernel verbatim.
//
// K1 LDS element map (float S[13296] = 53184 B, 3 blocks/CU):
//  WbL  bf16 el 0..4351       conv2 weights [oc][K'=k*16+ic], row stride 136
//  Wc1L bf16 el 4352..4863    conv1 weights (sign-flipped), K'=1..15 taps
//  SA   el 4864..15591  (w2432..7795): fxb rel el 0..4495 (flux at rel x+8,
//       rel 0..7 & 4456..4495 zero), h1T rel el 4496..10215 (rows 0..3 &
//       282..285 zero), featU_A w7540..7795
//  SB   el 15592..26319 (w7796..13159): same layout; featU_B w12904..13159
//  scratch w13160..13295: s_hiddenA w13160, s_hiddenB w13224,
//       s_redA w13288, s_redB w13292
// Overreads (re-traced): stage1 fxb rel<=4507 -> h1T rows 0..3 (zero);
// stage2 h1T rows 286..294 -> featU words (value-masked by j>138, in-bounds).
#define H1T_EL 4496   // rel offset inside a sample region (elements)
#define WB_EL  0
#define WC1_EL 10216  // (fused fallback map only)
#define FTW    5364   // (fused fallback map only)
#define RGN    5620   // (fused fallback map only)

typedef __attribute__((ext_vector_type(4))) short short4v;
typedef __attribute__((ext_vector_type(8))) short short8;
typedef __attribute__((ext_vector_type(4))) float f32x4;
union FragU { short8 v; short4v h[2]; };

__device__ __forceinline__ short f2bf(float x) {   // fp32 -> bf16 (RNE)
    unsigned u = __float_as_uint(x);
    u += 0x7FFFu + ((u >> 16) & 1u);
    return (short)(u >> 16);
}

__device__ __forceinline__ short8 pack8(float4 a, float4 b) {
    short8 v;
    v[0] = f2bf(a.x); v[1] = f2bf(a.y); v[2] = f2bf(a.z); v[3] = f2bf(a.w);
    v[4] = f2bf(b.x); v[5] = f2bf(b.y); v[6] = f2bf(b.z); v[7] = f2bf(b.w);
    return v;
}

// CNOT-ring permutation (one layer of 8 CNOTs composed). Linear over GF(2).
constexpr int permsrc_c(int x) {
    for (int q = 7; q >= 0; --q) {
        int cb = 7 - q, tb = 7 - ((q + 1) & 7);
        x ^= ((x >> cb) & 1) << tb;
    }
    return x;
}
constexpr int P40 = permsrc_c(0x40);
constexpr int P80 = permsrc_c(0x80);
constexpr int PC0 = permsrc_c(0xC0);   // == P40 ^ P80 (GF(2)-linear)

__device__ __forceinline__ int permsrc(int x) {
    #pragma unroll
    for (int q = 7; q >= 0; --q) {
        int cb = 7 - q, tb = 7 - ((q + 1) & 7);
        x ^= ((x >> cb) & 1) << tb;
    }
    return x;
}

// ======================= K1: persistent conv/proj/norm -> ws ================
__global__ __launch_bounds__(256, 3)
void aec_conv_kernel(const float* __restrict__ flux,
                     const float* __restrict__ conv1_w,
                     const float* __restrict__ bn1_g, const float* __restrict__ bn1_b,
                     const float* __restrict__ conv2_w,
                     const float* __restrict__ bn2_g, const float* __restrict__ bn2_b,
                     const float* __restrict__ proj_w1, const float* __restrict__ proj_b1,
                     const float* __restrict__ proj_w2, const float* __restrict__ proj_b2,
                     float* __restrict__ ws, int np)
{
    const int tid = threadIdx.x;

    __shared__ __align__(16) float S[13296];
    float* SAr       = S + 2432;     // SA region base (words)
    float* SBr       = S + 7796;     // SB region base (words)
    float* featUA    = S + 7540;
    float* featUB    = S + 12904;
    float* s_hiddenA = S + 13160;
    float* s_hiddenB = S + 13224;
    float* s_redA    = S + 13288;
    float* s_redB    = S + 13292;

    const float BN_RSQ = 0.9999950000374997f;     // 1/sqrt(1+1e-5)

    const int lane = tid & 63;
    const int wid  = tid >> 6;
    const int col  = lane & 15;
    const int quad = lane >> 4;

    // -------- once per block: pads, featU zeros, weight staging --------
    featUA[tid] = 0.0f;
    featUB[tid] = 0.0f;
    if (tid < 4)       { SAr[tid] = 0.0f;        SBr[tid] = 0.0f; }        // fxb el 0..7
    else if (tid < 64) { SAr[2224 + tid] = 0.0f; SBr[2224 + tid] = 0.0f; } // fxb tail + h1T rows 0..3
    else if (tid < 104){ SAr[5004 + tid] = 0.0f; SBr[5004 + tid] = 0.0f; } // h1T rows 282..285
    {
        // Wc1L: k'=0 zero, k'=1..15 = sgn*conv1_w, 16..31 zero. Sign flip so
        // every effective bn1 scale >= 0 (maxpool commutes with the affine).
        const int oc = tid >> 4;
        const int q  = tid & 15;
        const float sgn = (bn1_g[oc] >= 0.0f) ? 1.0f : -1.0f;
        const int k0 = 2 * q, k1 = 2 * q + 1;
        const short e0 = (k0 >= 1 && k0 <= 15) ? f2bf(sgn * conv1_w[oc * 15 + k0 - 1]) : (short)0;
        const short e1 = (k1 <= 15)            ? f2bf(sgn * conv1_w[oc * 15 + k1 - 1]) : (short)0;
        const unsigned pk = (unsigned short)e0 | ((unsigned)(unsigned short)e1 << 16);
        *(unsigned*)((short*)S + 4352 + oc * 32 + 2 * q) = pk;
    }
    {
        // WbL[oc][K'=k*16+ic] bf16, row stride 136 (k==7 row zero) — direct.
        const int oc = tid >> 3;
        const int k  = tid & 7;
        short8 w0, w1;
        #pragma unroll
        for (int e = 0; e < 8; ++e) {
            w0[e] = (k < 7) ? f2bf(conv2_w[oc * 112 + e * 7 + k])       : (short)0;
            w1[e] = (k < 7) ? f2bf(conv2_w[oc * 112 + (8 + e) * 7 + k]) : (short)0;
        }
        short8* dst = (short8*)((char*)S + (oc * 136 + k * 16) * 2);
        dst[0] = w0; dst[1] = w1;
    }

    int pr = blockIdx.x;              // current pair index
    {
        // prologue flux staging for pair pr (both samples)
        const float4* fgA = (const float4*)(flux + (size_t)(2 * pr) * L0);
        const float4* fgB = (const float4*)(flux + (size_t)(2 * pr + 1) * L0);
        short* fxA = (short*)S + 4864;
        short* fxB = (short*)S + 15592;
        for (int t = tid; t < 556; t += 256) {
            float4 a0 = fgA[2 * t], a1 = fgA[2 * t + 1];
            float4 b0 = fgB[2 * t], b1 = fgB[2 * t + 1];
            *(short8*)(fxA + 8 + 8 * t) = pack8(a0, a1);
            *(short8*)(fxB + 8 + 8 * t) = pack8(b0, b1);
        }
    }
    __syncthreads();   // weights + pads + pair-0 flux visible

    // loop-invariant bn factors + conv1 fragment
    const float gsc = fabsf(bn1_g[col]) * BN_RSQ;
    const float gbt = bn1_b[col];
    const float sc0 = bn2_g[col] * BN_RSQ,      bt0 = bn2_b[col];
    const float sc1 = bn2_g[col + 16] * BN_RSQ, bt1 = bn2_b[col + 16];
    const short8 wfrag = *(const short8*)((const short*)S + 4352 + col * 32 + quad * 8);

    const float4 z4 = make_float4(0.f, 0.f, 0.f, 0.f);

    for (;;) {
        const int  prn = pr + GRIDSZ;
        const bool hn  = (prn < np);          // block-uniform

        // ---------------- stage 1: conv1 MFMA + pool + bn, A/B interleaved ----
        {
            const short* fxA = (const short*)S + 4864;
            const short* fxB = (const short*)S + 15592;
            for (int nt = wid; nt < 70; nt += 4) {
                const int jl = nt * 16 + col;
                FragU xuA, xuB;
                xuA.h[0] = *(const short4v*)(fxA + 4 * jl + quad * 8);
                xuA.h[1] = *(const short4v*)(fxA + 4 * jl + quad * 8 + 4);
                xuB.h[0] = *(const short4v*)(fxB + 4 * jl + quad * 8);
                xuB.h[1] = *(const short4v*)(fxB + 4 * jl + quad * 8 + 4);
                f32x4 accA = {0.f, 0.f, 0.f, 0.f};
                f32x4 accB = {0.f, 0.f, 0.f, 0.f};
                accA = __builtin_amdgcn_mfma_f32_16x16x32_bf16(xuA.v, wfrag, accA, 0, 0, 0);
                accB = __builtin_amdgcn_mfma_f32_16x16x32_bf16(xuB.v, wfrag, accB, 0, 0, 0);
                const float mA = fmaxf(fmaxf(accA[0], accA[1]), fmaxf(accA[2], accA[3]));
                const float mB = fmaxf(fmaxf(accB[0], accB[1]), fmaxf(accB[2], accB[3]));
                const int pp = nt * 4 + quad;          // pooled position
                if (pp < L1P) {
                    *((short*)S + 4864  + H1T_EL + (4 + pp) * 20 + col) =
                        f2bf(fmaxf(mA * gsc + gbt, 0.0f));
                    *((short*)S + 15592 + H1T_EL + (4 + pp) * 20 + col) =
                        f2bf(fmaxf(mB * gsc + gbt, 0.0f));
                }
            }
        }
        __syncthreads();   // h1T complete; fxb now DEAD

        // ---- issue NEXT pair's flux loads NOW (fxb dead). Stage 2 has no
        //      global-memory ops, so its compute covers the load latency; the
        //      vmcnt wait lands at the pack/ds_write after stage 2. The live
        //      range crosses NO barrier (R20's spill fix).
        float4 pa0 = z4, pa1 = z4, pa2 = z4, pa3 = z4, pa4 = z4, pa5 = z4;
        float4 pb0 = z4, pb1 = z4, pb2 = z4, pb3 = z4, pb4 = z4, pb5 = z4;
        if (hn) {
            const float4* fgA = (const float4*)(flux + (size_t)(2 * prn) * L0);
            const float4* fgB = (const float4*)(flux + (size_t)(2 * prn + 1) * L0);
            pa0 = fgA[2 * tid];         pa1 = fgA[2 * tid + 1];
            pa2 = fgA[2 * (tid + 256)]; pa3 = fgA[2 * (tid + 256) + 1];
            pb0 = fgB[2 * tid];         pb1 = fgB[2 * tid + 1];
            pb2 = fgB[2 * (tid + 256)]; pb3 = fgB[2 * (tid + 256) + 1];
            if (tid < 44) {
                pa4 = fgA[2 * (tid + 512)]; pa5 = fgA[2 * (tid + 512) + 1];
                pb4 = fgB[2 * (tid + 512)]; pb5 = fgB[2 * (tid + 512) + 1];
            }
        }

        // ---------------- stage 2: conv2 MFMA + bn/relu + pool -----------------
        {
            const short* h1sA = (const short*)S + 4864  + H1T_EL;
            const short* h1sB = (const short*)S + 15592 + H1T_EL;
            const char*  wbc  = (const char*)S;         // WbL at el 0

            short8 wa0[4], wa1[4];
            #pragma unroll
            for (int kb = 0; kb < 4; ++kb) {
                wa0[kb] = *(const short8*)(wbc + (col * 136        + kb*32 + quad*8) * 2);
                wa1[kb] = *(const short8*)(wbc + ((16 + col) * 136 + kb*32 + quad*8) * 2);
            }

            for (int nt = wid; nt < 9; nt += 4) {
                const int n0 = nt * 16;
                f32x4 accA0 = {0.f,0.f,0.f,0.f}, accA1 = {0.f,0.f,0.f,0.f};
                f32x4 accB0 = {0.f,0.f,0.f,0.f}, accB1 = {0.f,0.f,0.f,0.f};
                #pragma unroll
                for (int kb = 0; kb < 4; ++kb) {
                    const int k   = 2 * kb + (quad >> 1);
                    const int ic0 = (quad & 1) * 8;
                    const int row = 2 * (n0 + col) + 1 + k;
                    FragU buA, buB;
                    buA.h[0] = *(const short4v*)(h1sA + row * 20 + ic0);
                    buA.h[1] = *(const short4v*)(h1sA + row * 20 + ic0 + 4);
                    buB.h[0] = *(const short4v*)(h1sB + row * 20 + ic0);
                    buB.h[1] = *(const short4v*)(h1sB + row * 20 + ic0 + 4);
                    accA0 = __builtin_amdgcn_mfma_f32_16x16x32_bf16(buA.v, wa0[kb], accA0, 0, 0, 0);
                    accA1 = __builtin_amdgcn_mfma_f32_16x16x32_bf16(buA.v, wa1[kb], accA1, 0, 0, 0);
                    accB0 = __builtin_amdgcn_mfma_f32_16x16x32_bf16(buB.v, wa0[kb], accB0, 0, 0, 0);
                    accB1 = __builtin_amdgcn_mfma_f32_16x16x32_bf16(buB.v, wa1[kb], accB1, 0, 0, 0);
                }
                const int   bk  = (8 * n0) / 139;
                const int   sBd = (139 * (bk + 1)) >> 3;
                const float rc0 = (bk == 2 || bk == 5) ? (1.0f/19.0f) : (1.0f/18.0f);
                const float rc1 = (bk == 1 || bk == 4) ? (1.0f/19.0f) : (1.0f/18.0f);
                float vaA0 = 0.f, vbA0 = 0.f, vaA1 = 0.f, vbA1 = 0.f;
                float vaB0 = 0.f, vbB0 = 0.f, vaB1 = 0.f, vbB1 = 0.f;
                #pragma unroll
                for (int r = 0; r < 4; ++r) {
                    const int j = n0 + quad * 4 + r;
                    float vA0 = fmaxf(accA0[r] * sc0 + bt0, 0.0f);
                    float vA1 = fmaxf(accA1[r] * sc1 + bt1, 0.0f);
                    float vB0 = fmaxf(accB0[r] * sc0 + bt0, 0.0f);
                    float vB1 = fmaxf(accB1[r] * sc1 + bt1, 0.0f);
                    if (j > 138) { vA0 = 0.0f; vA1 = 0.0f; vB0 = 0.0f; vB1 = 0.0f; }
                    if (j <= sBd) { vaA0 += vA0; vaA1 += vA1; vaB0 += vB0; vaB1 += vB1; }
                    if (j >= sBd) { vbA0 += vA0; vbA1 += vA1; vbB0 += vB0; vbB1 += vB1; }
                }
                vaA0 += __shfl_xor(vaA0, 16, 64); vaA0 += __shfl_xor(vaA0, 32, 64);
                vaA1 += __shfl_xor(vaA1, 16, 64); vaA1 += __shfl_xor(vaA1, 32, 64);
                vbA0 += __shfl_xor(vbA0, 16, 64); vbA0 += __shfl_xor(vbA0, 32, 64);
                vbA1 += __shfl_xor(vbA1, 16, 64); vbA1 += __shfl_xor(vbA1, 32, 64);
                vaB0 += __shfl_xor(vaB0, 16, 64); vaB0 += __shfl_xor(vaB0, 32, 64);
                vaB1 += __shfl_xor(vaB1, 16, 64); vaB1 += __shfl_xor(vaB1, 32, 64);
                vbB0 += __shfl_xor(vbB0, 16, 64); vbB0 += __shfl_xor(vbB0, 32, 64);
                vbB1 += __shfl_xor(vbB1, 16, 64); vbB1 += __shfl_xor(vbB1, 32, 64);
                if (quad == 0) {
                    atomicAdd(&featUA[col * 8 + bk],        vaA0 * rc0);
                    atomicAdd(&featUA[(col + 16) * 8 + bk], vaA1 * rc0);
                    atomicAdd(&featUB[col * 8 + bk],        vaB0 * rc0);
                    atomicAdd(&featUB[(col + 16) * 8 + bk], vaB1 * rc0);
                    if (bk < 7) {
                        atomicAdd(&featUA[col * 8 + bk + 1],        vbA0 * rc1);
                        atomicAdd(&featUA[(col + 16) * 8 + bk + 1], vbA1 * rc1);
                        atomicAdd(&featUB[col * 8 + bk + 1],        vbB0 * rc1);
                        atomicAdd(&featUB[(col + 16) * 8 + bk + 1], vbB1 * rc1);
                    }
                }
            }
        }
        // ---- pack + write prefetched pair into dead fxb (vmcnt wait lands
        //      here, ~2k cycles after issue — covered by stage 2) -------------
        if (hn) {
            short* fxA = (short*)S + 4864;
            short* fxB = (short*)S + 15592;
            *(short8*)(fxA + 8 + 8 * tid)         = pack8(pa0, pa1);
            *(short8*)(fxA + 8 + 8 * (tid + 256)) = pack8(pa2, pa3);
            *(short8*)(fxB + 8 + 8 * tid)         = pack8(pb0, pb1);
            *(short8*)(fxB + 8 + 8 * (tid + 256)) = pack8(pb2, pb3);
            if (tid < 44) {
                *(short8*)(fxA + 8 + 8 * (tid + 512)) = pack8(pa4, pa5);
                *(short8*)(fxB + 8 + 8 * (tid + 512)) = pack8(pb4, pb5);
            }
        }
        __syncthreads();   // featU complete + next-pair fxb published

        // ---------------- proj1 (256 -> 64), relu ------------------------------
        {
            const int o = tid >> 2, s = tid & 3;
            const float4* wg  = (const float4*)(proj_w1 + 64 * tid);
            const float4* xfA = (const float4*)(featUA + 64 * s);
            const float4* xfB = (const float4*)(featUB + 64 * s);
            float accA = 0.0f, accB = 0.0f;
            #pragma unroll
            for (int t = 0; t < 16; ++t) {
                float4 w4 = wg[t], a4 = xfA[t], b4 = xfB[t];
                accA += w4.x * a4.x + w4.y * a4.y + w4.z * a4.z + w4.w * a4.w;
                accB += w4.x * b4.x + w4.y * b4.y + w4.z * b4.z + w4.w * b4.w;
            }
            accA += __shfl_down(accA, 2, 64); accB += __shfl_down(accB, 2, 64);
            accA += __shfl_down(accA, 1, 64); accB += __shfl_down(accB, 1, 64);
            if (s == 0) {
                s_hiddenA[o] = fmaxf(accA + proj_b1[o], 0.0f);
                s_hiddenB[o] = fmaxf(accB + proj_b1[o], 0.0f);
            }
        }
        __syncthreads();   // s_hidden ready; featU consumed

        // re-zero featU for the next pair (published by the norm barrier below)
        featUA[tid] = 0.0f;
        featUB[tid] = 0.0f;

        // ---------------- proj2 (64 -> 256) + L2 normalize -> ws ---------------
        {
            const float4* wg  = (const float4*)(proj_w2 + 64 * tid);
            const float4* hfA = (const float4*)s_hiddenA;
            const float4* hfB = (const float4*)s_hiddenB;
            float accA = proj_b2[tid], accB = accA;
            #pragma unroll
            for (int t = 0; t < 16; ++t) {
                float4 w4 = wg[t], a4 = hfA[t], b4 = hfB[t];
                accA += w4.x * a4.x + w4.y * a4.y + w4.z * a4.z + w4.w * a4.w;
                accB += w4.x * b4.x + w4.y * b4.y + w4.z * b4.z + w4.w * b4.w;
            }
            float ssA = accA * accA, ssB = accB * accB;
            #pragma unroll
            for (int off = 32; off >= 1; off >>= 1) {
                ssA += __shfl_xor(ssA, off, 64);
                ssB += __shfl_xor(ssB, off, 64);
            }
            if ((tid & 63) == 0) { s_redA[tid >> 6] = ssA; s_redB[tid >> 6] = ssB; }
            __syncthreads();
            float sstA = s_redA[0] + s_redA[1] + s_redA[2] + s_redA[3];
            float sstB = s_redB[0] + s_redB[1] + s_redB[2] + s_redB[3];
            float nA = sqrtf(sstA), nB = sqrtf(sstB);
            float invA = 1.0f / fmaxf(nA, 1e-12f);
            float invB = 1.0f / fmaxf(nB, 1e-12f);
            float xiA = accA * invA, xiB = accB * invB;
            if (nA * invA < 1e-8f) xiA = 0.0625f;
            if (nB * invB < 1e-8f) xiB = 0.0625f;
            ws[(size_t)(2 * pr)     * SD + tid] = xiA;
            ws[(size_t)(2 * pr + 1) * SD + tid] = xiB;
        }

        if (!hn) break;
        pr = prn;          // fxb already holds pair prn (published at featU barrier)
    }
}

// ======================= K2: circuit + head (wave = sample) ================
// R13-verified math: 4 amps/lane (amp bits 6,7 = register index), q=0,1
// register-local, q=2..7 shuffle gates, CNOT perm via per-wave LDS scratch
// (intra-wave program-ordered, no barriers). One block barrier for s_U.
__global__ __launch_bounds__(256, 8)
void aec_circuit_kernel(const float* __restrict__ ws,
                        const float* __restrict__ scalars,
                        const float* __restrict__ qw,
                        const float* __restrict__ head_w1, const float* __restrict__ head_b1,
                        const float* __restrict__ head_bn_g, const float* __restrict__ head_bn_b,
                        const float* __restrict__ head_w2, const float* __restrict__ head_b2,
                        float* __restrict__ out)
{
    const int tid  = threadIdx.x;
    const int wid  = tid >> 6;
    const int lane = tid & 63;
    const int s    = blockIdx.x * 4 + wid;      // one wave = one sample

    __shared__ __align__(16) float s_U[NL * NQ * 8];   // 192 floats, shared
    __shared__ __align__(16) float scr[4][512];        // per-wave re/im scratch
    __shared__ float s_q4[4][8];

    const float BN_RSQ = 0.9999950000374997f;     // 1/sqrt(1+1e-5)

    if (tid < NL * NQ) {
        float phi = qw[tid * 3 + 0], th = qw[tid * 3 + 1], om = qw[tid * 3 + 2];
        float ch = cosf(0.5f * th), sh = sinf(0.5f * th);
        float a  = 0.5f * (phi + om), bb = 0.5f * (phi - om);
        float ca = cosf(a), sa = sinf(a), cb = cosf(bb), sb = sinf(bb);
        float* U = &s_U[tid * 8];
        U[0] =  ca * ch; U[1] = -sa * ch;   // U00
        U[2] = -cb * sh; U[3] = -sb * sh;   // U01
        U[4] =  cb * sh; U[5] = -sb * sh;   // U10
        U[6] =  ca * ch; U[7] =  sa * ch;   // U11
    }
    __syncthreads();   // the only block barrier

    float* areb = scr[wid];
    float* aimb = scr[wid] + 256;
    const int sPl = permsrc(lane);

    float xr[4], xi4[4];
    #pragma unroll
    for (int r = 0; r < 4; ++r) {
        xr[r]  = ws[(size_t)s * SD + 64 * r + lane];
        xi4[r] = 0.0f;
    }

    #pragma unroll
    for (int l = 0; l < NL; ++l) {
        // q=0: gate on bit7 -> register pairs (r, r^2)
        {
            const float* U = &s_U[(l * NQ + 0) * 8];
            #pragma unroll
            for (int b6 = 0; b6 < 2; ++b6) {
                const float i0r = xr[b6],      i0i = xi4[b6];
                const float i1r = xr[2 + b6],  i1i = xi4[2 + b6];
                xr[b6]      = U[0]*i0r - U[1]*i0i + U[2]*i1r - U[3]*i1i;
                xi4[b6]     = U[0]*i0i + U[1]*i0r + U[2]*i1i + U[3]*i1r;
                xr[2 + b6]  = U[4]*i0r - U[5]*i0i + U[6]*i1r - U[7]*i1i;
                xi4[2 + b6] = U[4]*i0i + U[5]*i0r + U[6]*i1i + U[7]*i1r;
            }
        }
        // q=1: gate on bit6 -> register pairs (r, r^1)
        {
            const float* U = &s_U[(l * NQ + 1) * 8];
            #pragma unroll
            for (int b7 = 0; b7 < 2; ++b7) {
                const int r0 = 2 * b7;
                const float i0r = xr[r0],      i0i = xi4[r0];
                const float i1r = xr[r0 + 1],  i1i = xi4[r0 + 1];
                xr[r0]      = U[0]*i0r - U[1]*i0i + U[2]*i1r - U[3]*i1i;
                xi4[r0]     = U[0]*i0i + U[1]*i0r + U[2]*i1i + U[3]*i1r;
                xr[r0 + 1]  = U[4]*i0r - U[5]*i0i + U[6]*i1r - U[7]*i1i;
                xi4[r0 + 1] = U[4]*i0i + U[5]*i0r + U[6]*i1i + U[7]*i1r;
            }
        }
        // q=2..7: lane-bit gates via shuffles, applied to all 4 regs
        #pragma unroll
        for (int q = 2; q < NQ; ++q) {
            const float* U = &s_U[(l * NQ + q) * 8];
            const int bp = 7 - q;
            const int bit = (lane >> bp) & 1;
            const float csr = bit ? U[6] : U[0];
            const float csi = bit ? U[7] : U[1];
            const float cpr = bit ? U[4] : U[2];
            const float cpi = bit ? U[5] : U[3];
            #pragma unroll
            for (int r = 0; r < 4; ++r) {
                const float pr_ = __shfl_xor(xr[r],  1 << bp, 64);
                const float pi_ = __shfl_xor(xi4[r], 1 << bp, 64);
                const float nr = csr * xr[r]  - csi * xi4[r] + cpr * pr_ - cpi * pi_;
                const float ni = csr * xi4[r] + csi * xr[r]  + cpr * pi_ + cpi * pr_;
                xr[r] = nr; xi4[r] = ni;
            }
        }
        // CNOT-ring permutation via per-wave LDS scratch (intra-wave, no barrier)
        #pragma unroll
        for (int r = 0; r < 4; ++r) {
            areb[64 * r + lane] = xr[r];
            aimb[64 * r + lane] = xi4[r];
        }
        const int s0 = sPl, s1 = sPl ^ P40, s2 = sPl ^ P80, s3 = sPl ^ PC0;
        xr[0] = areb[s0]; xi4[0] = aimb[s0];
        xr[1] = areb[s1]; xi4[1] = aimb[s1];
        xr[2] = areb[s2]; xi4[2] = aimb[s2];
        xr[3] = areb[s3]; xi4[3] = aimb[s3];
    }

    // Walsh-Hadamard Z expectations (R10-verified mapping)
    float* sq = s_q4[wid];
    {
        const float pr0 = xr[0]*xr[0] + xi4[0]*xi4[0];
        const float pr1 = xr[1]*xr[1] + xi4[1]*xi4[1];
        const float pr2 = xr[2]*xr[2] + xi4[2]*xi4[2];
        const float pr3 = xr[3]*xr[3] + xi4[3]*xi4[3];
        float t  = pr0 + pr1 + pr2 + pr3;
        float u6 = pr0 - pr1 + pr2 - pr3;   // sign = bit6 = r&1
        float u7 = pr0 + pr1 - pr2 - pr3;   // sign = bit7 = r>>1
        #pragma unroll
        for (int d = 0; d < 6; ++d) {
            const float p = __shfl_xor(t, 1 << d, 64);
            t = ((lane >> d) & 1) ? (p - t) : (t + p);
            u6 += __shfl_xor(u6, 1 << d, 64);
            u7 += __shfl_xor(u7, 1 << d, 64);
        }
        if (lane == 0) { sq[0] = u7; sq[1] = u6; }
        else if ((lane & (lane - 1)) == 0) {
            const int bp = 31 - __clz(lane);          // lane = 1<<bp, bp 0..5
            sq[7 - bp] = t;                           // <Z_q> with q = 7-bp
        }
    }
    // head layer 1 (lanes 0..31; sq read-after-write, same wave)
    float h = 0.0f;
    if (lane < 32) {
        float acc = head_b1[lane];
        #pragma unroll
        for (int k = 0; k < 8; ++k) acc += head_w1[lane * 14 + k] * sq[k];
        #pragma unroll
        for (int k = 0; k < 6; ++k) acc += head_w1[lane * 14 + 8 + k] * scalars[s * 6 + k];
        h = fmaxf(acc * (head_bn_g[lane] * BN_RSQ) + head_bn_b[lane], 0.0f);
    }
    // head layer 2: 3 dot-products over 32 h values via butterfly reduce
    float p0 = (lane < 32) ? h * head_w2[lane]      : 0.0f;
    float p1 = (lane < 32) ? h * head_w2[32 + lane] : 0.0f;
    float p2 = (lane < 32) ? h * head_w2[64 + lane] : 0.0f;
    #pragma unroll
    for (int d = 0; d < 6; ++d) {
        p0 += __shfl_xor(p0, 1 << d, 64);
        p1 += __shfl_xor(p1, 1 << d, 64);
        p2 += __shfl_xor(p2, 1 << d, 64);
    }
    if (lane < 3) {
        const float v = (lane == 0) ? p0 : ((lane == 1) ? p1 : p2);
        out[s * 3 + lane] = v + head_b2[lane];
    }
}

// ======================= Fallback: R16 fused kernel (verbatim) =============
__global__ __launch_bounds__(256, 3)
void aec_fused_kernel(const float* __restrict__ flux,
                      const float* __restrict__ scalars,
                      const float* __restrict__ conv1_w,
                      const float* __restrict__ bn1_g, const float* __restrict__ bn1_b,
                      const float* __restrict__ conv2_w,
                      const float* __restrict__ bn2_g, const float* __restrict__ bn2_b,
                      const float* __restrict__ proj_w1, const float* __restrict__ proj_b1,
                      const float* __restrict__ proj_w2, const float* __restrict__ proj_b2,
                      const float* __restrict__ qw,
                      const float* __restrict__ head_w1, const float* __restrict__ head_b1,
                      const float* __restrict__ head_bn_g, const float* __restrict__ head_bn_b,
                      const float* __restrict__ head_w2, const float* __restrict__ head_b2,
                      float* __restrict__ out)
{
    const int iA  = 2 * blockIdx.x;
    const int iB  = iA + 1;
    const int tid = threadIdx.x;

    __shared__ __align__(16) float S2[2 * RGN];
    float* SA = S2;
    float* SB = S2 + RGN;

    float* s_hiddenA = SA;           float* s_hiddenB = SB;
    float* s_redA    = SA + 64;      float* s_redB    = SB + 64;   // later wp
    float* s_qA      = SA + 96;      float* s_qB      = SB + 96;
    float* featUA    = SA + FTW;     float* featUB    = SB + FTW;
    float* s_U       = SA + FTW;

    const float BN_RSQ = 0.9999950000374997f;

    featUA[tid] = 0.0f;
    featUB[tid] = 0.0f;
    if (tid < 4)       { SA[tid] = 0.0f;        SB[tid] = 0.0f; }
    else if (tid < 64) { SA[2224 + tid] = 0.0f; SB[2224 + tid] = 0.0f; }
    else if (tid < 104){ SA[5004 + tid] = 0.0f; SB[5004 + tid] = 0.0f; }
    {
        const int oc = tid >> 4;
        const int q  = tid & 15;
        const float sgn = (bn1_g[oc] >= 0.0f) ? 1.0f : -1.0f;
        const int k0 = 2 * q, k1 = 2 * q + 1;
        const short e0 = (k0 >= 1 && k0 <= 15) ? f2bf(sgn * conv1_w[oc * 15 + k0 - 1]) : (short)0;
        const short e1 = (k1 <= 15)            ? f2bf(sgn * conv1_w[oc * 15 + k1 - 1]) : (short)0;
        const unsigned pk = (unsigned short)e0 | ((unsigned)(unsigned short)e1 << 16);
        *(unsigned*)((short*)SA + WC1_EL + oc * 32 + 2 * q) = pk;
    }
    short8 wbp0, wbp1;
    {
        const int oc = tid >> 3;
        const int k  = tid & 7;
        #pragma unroll
        for (int e = 0; e < 8; ++e) {
            wbp0[e] = (k < 7) ? f2bf(conv2_w[oc * 112 + e * 7 + k])       : (short)0;
            wbp1[e] = (k < 7) ? f2bf(conv2_w[oc * 112 + (8 + e) * 7 + k]) : (short)0;
        }
    }
    {
        const float4* fgA = (const float4*)(flux + (size_t)iA * L0);
        const float4* fgB = (const float4*)(flux + (size_t)iB * L0);
        short* fxA = (short*)SA;
        short* fxB = (short*)SB;
        for (int t = tid; t < 556; t += 256) {
            float4 a0 = fgA[2 * t], a1 = fgA[2 * t + 1];
            float4 b0 = fgB[2 * t], b1 = fgB[2 * t + 1];
            *(short8*)(fxA + 8 + 8 * t) = pack8(a0, a1);
            *(short8*)(fxB + 8 + 8 * t) = pack8(b0, b1);
        }
    }
    __syncthreads();

    {
        const int lane = tid & 63;
        const int wid  = tid >> 6;
        const int col  = lane & 15;
        const int quad = lane >> 4;
        const short* fxA = (const short*)SA;
        const short* fxB = (const short*)SB;
        const short8 wfrag = *(const short8*)((const short*)SA + WC1_EL + col * 32 + quad * 8);
        const float gsc = fabsf(bn1_g[col]) * BN_RSQ;
        const float gbt = bn1_b[col];

        for (int nt = wid; nt < 70; nt += 4) {
            const int jl = nt * 16 + col;
            FragU xuA, xuB;
            xuA.h[0] = *(const short4v*)(fxA + 4 * jl + quad * 8);
            xuA.h[1] = *(const short4v*)(fxA + 4 * jl + quad * 8 + 4);
            xuB.h[0] = *(const short4v*)(fxB + 4 * jl + quad * 8);
            xuB.h[1] = *(const short4v*)(fxB + 4 * jl + quad * 8 + 4);
            f32x4 accA = {0.f, 0.f, 0.f, 0.f};
            f32x4 accB = {0.f, 0.f, 0.f, 0.f};
            accA = __builtin_amdgcn_mfma_f32_16x16x32_bf16(xuA.v, wfrag, accA, 0, 0, 0);
            accB = __builtin_amdgcn_mfma_f32_16x16x32_bf16(xuB.v, wfrag, accB, 0, 0, 0);
            const float mA = fmaxf(fmaxf(accA[0], accA[1]), fmaxf(accA[2], accA[3]));
            const float mB = fmaxf(fmaxf(accB[0], accB[1]), fmaxf(accB[2], accB[3]));
            const int p = nt * 4 + quad;
            if (p < L1P) {
                *((short*)SA + H1T_EL + (4 + p) * 20 + col) =
                    f2bf(fmaxf(mA * gsc + gbt, 0.0f));
                *((short*)SB + H1T_EL + (4 + p) * 20 + col) =
                    f2bf(fmaxf(mB * gsc + gbt, 0.0f));
            }
        }
    }
    __syncthreads();

    {
        const int oc = tid >> 3;
        const int k  = tid & 7;
        short8* dst = (short8*)((char*)SA + (WB_EL + oc * 136 + k * 16) * 2);
        dst[0] = wbp0; dst[1] = wbp1;
    }
    __syncthreads();

    {
        const int lane = tid & 63;
        const int wid  = tid >> 6;
        const int col  = lane & 15;
        const int quad = lane >> 4;
        const short* h1sA = (const short*)SA + H1T_EL;
        const short* h1sB = (const short*)SB + H1T_EL;
        const char*  wbc  = (const char*)((const short*)SA + WB_EL);
        const float sc0 = bn2_g[col] * BN_RSQ,      bt0 = bn2_b[col];
        const float sc1 = bn2_g[col + 16] * BN_RSQ, bt1 = bn2_b[col + 16];

        short8 wa0[4], wa1[4];
        #pragma unroll
        for (int kb = 0; kb < 4; ++kb) {
            wa0[kb] = *(const short8*)(wbc + (col * 136        + kb*32 + quad*8) * 2);
            wa1[kb] = *(const short8*)(wbc + ((16 + col) * 136 + kb*32 + quad*8) * 2);
        }

        for (int nt = wid; nt < 9; nt += 4) {
            const int n0 = nt * 16;
            f32x4 accA0 = {0.f,0.f,0.f,0.f}, accA1 = {0.f,0.f,0.f,0.f};
            f32x4 accB0 = {0.f,0.f,0.f,0.f}, accB1 = {0.f,0.f,0.f,0.f};
            #pragma unroll
            for (int kb = 0; kb < 4; ++kb) {
                const int k   = 2 * kb + (quad >> 1);
                const int ic0 = (quad & 1) * 8;
                const int row = 2 * (n0 + col) + 1 + k;
                FragU buA, buB;
                buA.h[0] = *(const short4v*)(h1sA + row * 20 + ic0);
                buA.h[1] = *(const short4v*)(h1sA + row * 20 + ic0 + 4);
                buB.h[0] = *(const short4v*)(h1sB + row * 20 + ic0);
                buB.h[1] = *(const short4v*)(h1sB + row * 20 + ic0 + 4);
                accA0 = __builtin_amdgcn_mfma_f32_16x16x32_bf16(buA.v, wa0[kb], accA0, 0, 0, 0);
                accA1 = __builtin_amdgcn_mfma_f32_16x16x32_bf16(buA.v, wa1[kb], accA1, 0, 0, 0);
                accB0 = __builtin_amdgcn_mfma_f32_16x16x32_bf16(buB.v, wa0[kb], accB0, 0, 0, 0);
                accB1 = __builtin_amdgcn_mfma_f32_16x16x32_bf16(buB.v, wa1[kb], accB1, 0, 0, 0);
            }
            const int   bk  = (8 * n0) / 139;
            const int   sBd = (139 * (bk + 1)) >> 3;
            const float rc0 = (bk == 2 || bk == 5) ? (1.0f/19.0f) : (1.0f/18.0f);
            const float rc1 = (bk == 1 || bk == 4) ? (1.0f/19.0f) : (1.0f/18.0f);
            float vaA0 = 0.f, vbA0 = 0.f, vaA1 = 0.f, vbA1 = 0.f;
            float vaB0 = 0.f, vbB0 = 0.f, vaB1 = 0.f, vbB1 = 0.f;
            #pragma unroll
            for (int r = 0; r < 4; ++r) {
                const int j = n0 + quad * 4 + r;
                float vA0 = fmaxf(accA0[r] * sc0 + bt0, 0.0f);
                float vA1 = fmaxf(accA1[r] * sc1 + bt1, 0.0f);
                float vB0 = fmaxf(accB0[r] * sc0 + bt0, 0.0f);
                float vB1 = fmaxf(accB1[r] * sc1 + bt1, 0.0f);
                if (j > 138) { vA0 = 0.0f; vA1 = 0.0f; vB0 = 0.0f; vB1 = 0.0f; }
                if (j <= sBd) { vaA0 += vA0; vaA1 += vA1; vaB0 += vB0; vaB1 += vB1; }
                if (j >= sBd) { vbA0 += vA0; vbA1 += vA1; vbB0 += vB0; vbB1 += vB1; }
            }
            vaA0 += __shfl_xor(vaA0, 16, 64); vaA0 += __shfl_xor(vaA0, 32, 64);
            vaA1 += __shfl_xor(vaA1, 16, 64); vaA1 += __shfl_xor(vaA1, 32, 64);
            vbA0 += __shfl_xor(vbA0, 16, 64); vbA0 += __shfl_xor(vbA0, 32, 64);
            vbA1 += __shfl_xor(vbA1, 16, 64); vbA1 += __shfl_xor(vbA1, 32, 64);
            vaB0 += __shfl_xor(vaB0, 16, 64); vaB0 += __shfl_xor(vaB0, 32, 64);
            vaB1 += __shfl_xor(vaB1, 16, 64); vaB1 += __shfl_xor(vaB1, 32, 64);
            vbB0 += __shfl_xor(vbB0, 16, 64); vbB0 += __shfl_xor(vbB0, 32, 64);
            vbB1 += __shfl_xor(vbB1, 16, 64); vbB1 += __shfl_xor(vbB1, 32, 64);
            if (quad == 0) {
                atomicAdd(&featUA[col * 8 + bk],        vaA0 * rc0);
                atomicAdd(&featUA[(col + 16) * 8 + bk], vaA1 * rc0);
                atomicAdd(&featUB[col * 8 + bk],        vaB0 * rc0);
                atomicAdd(&featUB[(col + 16) * 8 + bk], vaB1 * rc0);
                if (bk < 7) {
                    atomicAdd(&featUA[col * 8 + bk + 1],        vbA0 * rc1);
                    atomicAdd(&featUA[(col + 16) * 8 + bk + 1], vbA1 * rc1);
                    atomicAdd(&featUB[col * 8 + bk + 1],        vbB0 * rc1);
                    atomicAdd(&featUB[(col + 16) * 8 + bk + 1], vbB1 * rc1);
                }
            }
        }
    }
    __syncthreads();

    {
        const int o = tid >> 2, s = tid & 3;
        const float4* wg  = (const float4*)(proj_w1 + 64 * tid);
        const float4* xfA = (const float4*)(featUA + 64 * s);
        const float4* xfB = (const float4*)(featUB + 64 * s);
        float accA = 0.0f, accB = 0.0f;
        #pragma unroll
        for (int t = 0; t < 16; ++t) {
            float4 w4 = wg[t], a4 = xfA[t], b4 = xfB[t];
            accA += w4.x * a4.x + w4.y * a4.y + w4.z * a4.z + w4.w * a4.w;
            accB += w4.x * b4.x + w4.y * b4.y + w4.z * b4.z + w4.w * b4.w;
        }
        accA += __shfl_down(accA, 2, 64); accB += __shfl_down(accB, 2, 64);
        accA += __shfl_down(accA, 1, 64); accB += __shfl_down(accB, 1, 64);
        if (s == 0) {
            s_hiddenA[o] = fmaxf(accA + proj_b1[o], 0.0f);
            s_hiddenB[o] = fmaxf(accB + proj_b1[o], 0.0f);
        }
    }
    __syncthreads();

    if (tid < NL * NQ) {
        float phi = qw[tid * 3 + 0], th = qw[tid * 3 + 1], om = qw[tid * 3 + 2];
        float ch = cosf(0.5f * th), sh = sinf(0.5f * th);
        float a  = 0.5f * (phi + om), bb = 0.5f * (phi - om);
        float ca = cosf(a), sa = sinf(a), cb = cosf(bb), sb = sinf(bb);
        float* U = &s_U[tid * 8];
        U[0] =  ca * ch; U[1] = -sa * ch;
        U[2] = -cb * sh; U[3] = -sb * sh;
        U[4] =  cb * sh; U[5] = -sb * sh;
        U[6] =  ca * ch; U[7] =  sa * ch;
    }

    float reA, reB;
    {
        const float4* wg  = (const float4*)(proj_w2 + 64 * tid);
        const float4* hfA = (const float4*)s_hiddenA;
        const float4* hfB = (const float4*)s_hiddenB;
        float accA = proj_b2[tid], accB = accA;
        #pragma unroll
        for (int t = 0; t < 16; ++t) {
            float4 w4 = wg[t], a4 = hfA[t], b4 = hfB[t];
            accA += w4.x * a4.x + w4.y * a4.y + w4.z * a4.z + w4.w * a4.w;
            accB += w4.x * b4.x + w4.y * b4.y + w4.z * b4.z + w4.w * b4.w;
        }
        float ssA = accA * accA, ssB = accB * accB;
        #pragma unroll
        for (int off = 32; off >= 1; off >>= 1) {
            ssA += __shfl_xor(ssA, off, 64);
            ssB += __shfl_xor(ssB, off, 64);
        }
        if ((tid & 63) == 0) { s_redA[tid >> 6] = ssA; s_redB[tid >> 6] = ssB; }
        __syncthreads();
        float sstA = s_redA[0] + s_redA[1] + s_redA[2] + s_redA[3];
        float sstB = s_redB[0] + s_redB[1] + s_redB[2] + s_redB[3];
        float nA = sqrtf(sstA), nB = sqrtf(sstB);
        float invA = 1.0f / fmaxf(nA, 1e-12f);
        float invB = 1.0f / fmaxf(nB, 1e-12f);
        float xiA = accA * invA, xiB = accB * invB;
        if (nA * invA < 1e-8f) xiA = 0.0625f;
        if (nB * invB < 1e-8f) xiB = 0.0625f;
        reA = xiA; reB = xiB;
    }

    float2* ampcA = (float2*)(SA + 256);
    float2* ampcB = (float2*)(SB + 256);
    float*  wpA   = SA + 64;
    float*  wpB   = SB + 64;

    const int lane = tid & 63;
    const int w    = tid >> 6;
    const int b7   = w >> 1, b6 = w & 1;
    const int sl   = permsrc(lane);
    const int pw   = (b6 ? P40 : 0) ^ (b7 ? P80 : 0);

    ampcA[tid] = make_float2(reA, 0.0f);
    ampcB[tid] = make_float2(reB, 0.0f);
    __syncthreads();

    float arA = 0.0f, aiA = 0.0f, arB = 0.0f, aiB = 0.0f;
    #pragma unroll
    for (int l = 0; l < NL; ++l) {
        float oAr[4], oAi[4], oBr[4], oBi[4];
        #pragma unroll
        for (int j = 0; j < 4; ++j) {
            const int src = (l == 0) ? (lane + 64 * j)
                                     : (sl ^ ((j & 1 ? P40 : 0) ^ (j & 2 ? P80 : 0)));
            const float2 vA = ampcA[src];
            const float2 vB = ampcB[src];
            oAr[j] = vA.x; oAi[j] = (l == 0) ? 0.0f : vA.y;
            oBr[j] = vB.x; oBi[j] = (l == 0) ? 0.0f : vB.y;
        }
        {
            const float* U0 = &s_U[(l * NQ + 0) * 8];
            const float* U1 = &s_U[(l * NQ + 1) * 8];
            const float a0r = b7 ? U0[4] : U0[0], a0i = b7 ? U0[5] : U0[1];
            const float a1r = b7 ? U0[6] : U0[2], a1i = b7 ? U0[7] : U0[3];
            const float c0r = b6 ? U1[4] : U1[0], c0i = b6 ? U1[5] : U1[1];
            const float c1r = b6 ? U1[6] : U1[2], c1i = b6 ? U1[7] : U1[3];
            const float tA0r = a0r*oAr[0] - a0i*oAi[0] + a1r*oAr[2] - a1i*oAi[2];
            const float tA0i = a0r*oAi[0] + a0i*oAr[0] + a1r*oAi[2] + a1i*oAr[2];
            const float tA1r = a0r*oAr[1] - a0i*oAi[1] + a1r*oAr[3] - a1i*oAi[3];
            const float tA1i = a0r*oAi[1] + a0i*oAr[1] + a1r*oAi[3] + a1i*oAr[3];
            arA = c0r*tA0r - c0i*tA0i + c1r*tA1r - c1i*tA1i;
            aiA = c0r*tA0i + c0i*tA0r + c1r*tA1i + c1i*tA1r;
            const float tB0r = a0r*oBr[0] - a0i*oBi[0] + a1r*oBr[2] - a1i*oBi[2];
            const float tB0i = a0r*oBi[0] + a0i*oBr[0] + a1r*oBi[2] + a1i*oBr[2];
            const float tB1r = a0r*oBr[1] - a0i*oBi[1] + a1r*oBr[3] - a1i*oBi[3];
            const float tB1i = a0r*oBi[1] + a0i*oBr[1] + a1r*oBi[3] + a1i*oBr[3];
            arB = c0r*tB0r - c0i*tB0i + c1r*tB1r - c1i*tB1i;
            aiB = c0r*tB0i + c0i*tB0r + c1r*tB1i + c1i*tB1r;
        }
        #pragma unroll
        for (int q = 2; q < NQ; ++q) {
            const float* U = &s_U[(l * NQ + q) * 8];
            const int bp  = 7 - q;
            const int bit = (lane >> bp) & 1;
            const float csr = bit ? U[6] : U[0];
            const float csi = bit ? U[7] : U[1];
            const float cpr = bit ? U[4] : U[2];
            const float cpi = bit ? U[5] : U[3];
            const float pAr = __shfl_xor(arA, 1 << bp, 64);
            const float pAi = __shfl_xor(aiA, 1 << bp, 64);
            const float pBr = __shfl_xor(arB, 1 << bp, 64);
            const float pBi = __shfl_xor(aiB, 1 << bp, 64);
            const float nAr = csr * arA - csi * aiA + cpr * pAr - cpi * pAi;
            const float nAi = csr * aiA + csi * arA + cpr * pAi + cpi * pAr;
            const float nBr = csr * arB - csi * aiB + cpr * pBr - cpi * pBi;
            const float nBi = csr * aiB + csi * arB + cpr * pBi + cpi * pBr;
            arA = nAr; aiA = nAi; arB = nBr; aiB = nBi;
        }
        __syncthreads();
        ampcA[tid] = make_float2(arA, aiA);
        ampcB[tid] = make_float2(arB, aiB);
        __syncthreads();
    }

    {
        const float2 vA = ampcA[sl ^ pw];
        const float2 vB = ampcB[sl ^ pw];
        arA = vA.x; aiA = vA.y; arB = vB.x; aiB = vB.y;
    }

    {
        const float pA = arA * arA + aiA * aiA;
        const float pB = arB * arB + aiB * aiB;
        float tA = pA, tB = pB;
        #pragma unroll
        for (int d = 0; d < 6; ++d) {
            const float sAs = __shfl_xor(tA, 1 << d, 64);
            const float sBs = __shfl_xor(tB, 1 << d, 64);
            tA = ((lane >> d) & 1) ? (sAs - tA) : (tA + sAs);
            tB = ((lane >> d) & 1) ? (sBs - tB) : (tB + sBs);
        }
        if (lane == 0) { wpA[w * 7] = tA; wpB[w * 7] = tB; }
        else if ((lane & (lane - 1)) == 0) {
            const int d = 31 - __clz(lane);
            wpA[w * 7 + 1 + d] = tA;
            wpB[w * 7 + 1 + d] = tB;
        }
    }
    __syncthreads();

    if (tid < 128) {
        const int sm = tid >> 6;
        const float* wpp = sm ? wpB : wpA;
        float* sq        = sm ? s_qB : s_qA;
        const int bb     = sm ? iB : iA;
        if (lane < 8) {
            float v;
            if (lane == 0)      v = wpp[0] + wpp[7] - wpp[14] - wpp[21];
            else if (lane == 1) v = wpp[0] - wpp[7] + wpp[14] - wpp[21];
            else {
                const int d = 7 - lane;
                v = wpp[1 + d] + wpp[8 + d] + wpp[15 + d] + wpp[22 + d];
            }
            sq[lane] = v;
        }
        float h = 0.0f;
        if (lane < 32) {
            float acc = head_b1[lane];
            #pragma unroll
            for (int k = 0; k < 8; ++k) acc += head_w1[lane * 14 + k] * sq[k];
            #pragma unroll
            for (int k = 0; k < 6; ++k) acc += head_w1[lane * 14 + 8 + k] * scalars[bb * 6 + k];
            h = fmaxf(acc * (head_bn_g[lane] * BN_RSQ) + head_bn_b[lane], 0.0f);
        }
        float p0 = (lane < 32) ? h * head_w2[lane]      : 0.0f;
        float p1 = (lane < 32) ? h * head_w2[32 + lane] : 0.0f;
        float p2 = (lane < 32) ? h * head_w2[64 + lane] : 0.0f;
        #pragma unroll
        for (int d = 0; d < 6; ++d) {
            p0 += __shfl_xor(p0, 1 << d, 64);
            p1 += __shfl_xor(p1, 1 << d, 64);
            p2 += __shfl_xor(p2, 1 << d, 64);
        }
        if (lane < 3) {
            const float v = (lane == 0) ? p0 : ((lane == 1) ? p1 : p2);
            out[bb * 3 + lane] = v + head_b2[lane];
        }
    }
}

extern "C" void kernel_launch(void* const* d_in, const int* in_sizes, int n_in,
                              void* d_out, int out_size, void* d_ws, size_t ws_size,
                              hipStream_t stream) {
    const float* flux      = (const float*)d_in[0];
    const float* scalars   = (const float*)d_in[1];
    const float* conv1_w   = (const float*)d_in[2];
    const float* bn1_g     = (const float*)d_in[3];
    const float* bn1_b     = (const float*)d_in[4];
    const float* conv2_w   = (const float*)d_in[5];
    const float* bn2_g     = (const float*)d_in[6];
    const float* bn2_b     = (const float*)d_in[7];
    const float* proj_w1   = (const float*)d_in[8];
    const float* proj_b1   = (const float*)d_in[9];
    const float* proj_w2   = (const float*)d_in[10];
    const float* proj_b2   = (const float*)d_in[11];
    const float* q_weights = (const float*)d_in[12];
    const float* head_w1   = (const float*)d_in[13];
    const float* head_b1   = (const float*)d_in[14];
    const float* head_bn_g = (const float*)d_in[15];
    const float* head_bn_b = (const float*)d_in[16];
    const float* head_w2   = (const float*)d_in[17];
    const float* head_b2   = (const float*)d_in[18];

    const int B = in_sizes[0] / L0;   // 4096
    const int np = B / 2;             // 2048 pairs
    const size_t need = (size_t)B * SD * sizeof(float);

    if (d_ws != nullptr && ws_size >= need && np >= GRIDSZ) {
        aec_conv_kernel<<<dim3(GRIDSZ), dim3(256), 0, stream>>>(
            flux, conv1_w, bn1_g, bn1_b, conv2_w, bn2_g, bn2_b,
            proj_w1, proj_b1, proj_w2, proj_b2, (float*)d_ws, np);
        aec_circuit_kernel<<<dim3(B / 4), dim3(256), 0, stream>>>(
            (const float*)d_ws, scalars, q_weights,
            head_w1, head_b1, head_bn_g, head_bn_b, head_w2, head_b2,
            (float*)d_out);
    } else {
        aec_fused_kernel<<<dim3(B / 2), dim3(256), 0, stream>>>(
            flux, scalars, conv1_w, bn1_g, bn1_b, conv2_w, bn2_g, bn2_b,
            proj_w1, proj_b1, proj_w2, proj_b2, q_weights,
            head_w1, head_b1, head_bn_g, head_bn_b, head_w2, head_b2,
            (float*)d_out);
    }
}

// Round 17
// 199.941 us; speedup vs baseline: 1.2562x; 1.2562x over previous
//
#include <hip/hip_runtime.h>
#include <math.h>

// Problem constants (fixed by reference setup_inputs)
#define L0   4448   // flux length
#define L1P  278    // after conv1(stride4,pad7)->1112 then maxpool4
#define L2   139    // after conv2(stride2,pad3) on 278
#define NQ   8
#define NL   3
#define SD   256

// R22 = R16 (measured best: 201.5 us harness / 92.9 us device) with ONE change:
// flux staging unrolled as issue-all-loads-then-pack (3x outstanding loads,
// short barrier-free live range — the spill-proof form of the prefetch idea).
//
// R16: TWO samples per block (iA=2b, iB=2b+1), mirrored LDS regions SA/SB of
// 5620 words each. Weights shared: Wc1, Wb in SA only; s_U in SA only;
// proj/head weights loaded once and dotted against both samples (ILP x2).
//
// Per-region element/word map (words rel. to region base):
//  fxb  bf16[4496]      el 0..4495      flux at el x+8; el 0..7 & 4456..4575 zero
//  h1T  bf16[286][20]   el 4496..10215  rows 0..3 & 282..285 zero (also fxb pad)
//  Wc1  bf16[16][32]    el 10216..10727 (SA ONLY; SB slot garbage, read only by
//                       the value-masked stage-2 nt=8 overread)
//  featU f32[256]       words 5364..5619 (s_U alias in SA after proj1 — R4 inv.)
//  Wb   bf16[32][136]   el 0..4351 (SA ONLY) — written after stage 1 into dead fxb_A
// Post-stage-2 aliases in each region (fxb/Wb dead): s_hidden w0..63,
// s_red/wp w64..95, s_q w96..103, ampc float2[256] w256..767.
#define H1T_EL 4496
#define WB_EL  0
#define WC1_EL 10216
#define FTW    5364
#define RGN    5620

typedef __attribute__((ext_vector_type(4))) short short4v;
typedef __attribute__((ext_vector_type(8))) short short8;
typedef __attribute__((ext_vector_type(4))) float f32x4;
union FragU { short8 v; short4v h[2]; };

__device__ __forceinline__ short f2bf(float x) {   // fp32 -> bf16 (RNE)
    unsigned u = __float_as_uint(x);
    u += 0x7FFFu + ((u >> 16) & 1u);
    return (short)(u >> 16);
}

__device__ __forceinline__ short8 pack8(float4 a, float4 b) {
    short8 v;
    v[0] = f2bf(a.x); v[1] = f2bf(a.y); v[2] = f2bf(a.z); v[3] = f2bf(a.w);
    v[4] = f2bf(b.x); v[5] = f2bf(b.y); v[6] = f2bf(b.z); v[7] = f2bf(b.w);
    return v;
}

// CNOT-ring permutation (one layer of 8 CNOTs composed). Linear over GF(2).
constexpr int permsrc_c(int x) {
    for (int q = 7; q >= 0; --q) {
        int cb = 7 - q, tb = 7 - ((q + 1) & 7);
        x ^= ((x >> cb) & 1) << tb;
    }
    return x;
}
constexpr int P40 = permsrc_c(0x40);
constexpr int P80 = permsrc_c(0x80);
constexpr int PC0 = permsrc_c(0xC0);   // == P40 ^ P80 (GF(2)-linear)

__device__ __forceinline__ int permsrc(int x) {
    #pragma unroll
    for (int q = 7; q >= 0; --q) {
        int cb = 7 - q, tb = 7 - ((q + 1) & 7);
        x ^= ((x >> cb) & 1) << tb;
    }
    return x;
}

__global__ __launch_bounds__(256, 3)
void aec_fused_kernel(const float* __restrict__ flux,
                      const float* __restrict__ scalars,
                      const float* __restrict__ conv1_w,
                      const float* __restrict__ bn1_g, const float* __restrict__ bn1_b,
                      const float* __restrict__ conv2_w,
                      const float* __restrict__ bn2_g, const float* __restrict__ bn2_b,
                      const float* __restrict__ proj_w1, const float* __restrict__ proj_b1,
                      const float* __restrict__ proj_w2, const float* __restrict__ proj_b2,
                      const float* __restrict__ qw,
                      const float* __restrict__ head_w1, const float* __restrict__ head_b1,
                      const float* __restrict__ head_bn_g, const float* __restrict__ head_bn_b,
                      const float* __restrict__ head_w2, const float* __restrict__ head_b2,
                      float* __restrict__ out)
{
    const int iA  = 2 * blockIdx.x;
    const int iB  = iA + 1;
    const int tid = threadIdx.x;

    __shared__ __align__(16) float S2[2 * RGN];
    float* SA = S2;
    float* SB = S2 + RGN;

    float* s_hiddenA = SA;           float* s_hiddenB = SB;
    float* s_redA    = SA + 64;      float* s_redB    = SB + 64;   // later wp
    float* s_qA      = SA + 96;      float* s_qB      = SB + 96;
    float* featUA    = SA + FTW;     float* featUB    = SB + FTW;
    float* s_U       = SA + FTW;     // gates overwrite featUA AFTER proj1 (R4 inv.)

    const float BN_RSQ = 0.9999950000374997f;     // 1/sqrt(1+1e-5)

    // ---------------- stage 0: zeros + weight staging + flux staging ----------
    featUA[tid] = 0.0f;
    featUB[tid] = 0.0f;
    if (tid < 4)       { SA[tid] = 0.0f;        SB[tid] = 0.0f; }
    else if (tid < 64) { SA[2224 + tid] = 0.0f; SB[2224 + tid] = 0.0f; }
    else if (tid < 104){ SA[5004 + tid] = 0.0f; SB[5004 + tid] = 0.0f; }
    {
        // Wc1 (SHARED, SA only): k'=0 zero, k'=1..15 = sgn*conv1_w, 16..31 zero.
        const int oc = tid >> 4;
        const int q  = tid & 15;
        const float sgn = (bn1_g[oc] >= 0.0f) ? 1.0f : -1.0f;
        const int k0 = 2 * q, k1 = 2 * q + 1;
        const short e0 = (k0 >= 1 && k0 <= 15) ? f2bf(sgn * conv1_w[oc * 15 + k0 - 1]) : (short)0;
        const short e1 = (k1 <= 15)            ? f2bf(sgn * conv1_w[oc * 15 + k1 - 1]) : (short)0;
        const unsigned pk = (unsigned short)e0 | ((unsigned)(unsigned short)e1 << 16);
        *(unsigned*)((short*)SA + WC1_EL + oc * 32 + 2 * q) = pk;
    }
    // Wb prefetch to REGISTERS (SHARED; ds_write into dead fxb_A after stage 1).
    short8 wbp0, wbp1;
    {
        const int oc = tid >> 3;
        const int k  = tid & 7;
        #pragma unroll
        for (int e = 0; e < 8; ++e) {
            wbp0[e] = (k < 7) ? f2bf(conv2_w[oc * 112 + e * 7 + k])       : (short)0;
            wbp1[e] = (k < 7) ? f2bf(conv2_w[oc * 112 + (8 + e) * 7 + k]) : (short)0;
        }
    }
    {
        // flux -> bf16 LDS, BOTH samples. R22: unrolled issue-all-then-pack —
        // up to 12 float4 loads in flight per thread (vs ~2-4 in the strided
        // loop); live range is short and crosses no barrier (spill-proof).
        const float4* fgA = (const float4*)(flux + (size_t)iA * L0);
        const float4* fgB = (const float4*)(flux + (size_t)iB * L0);
        short* fxA = (short*)SA;
        short* fxB = (short*)SB;
        float4 a0 = fgA[2 * tid];         float4 a1 = fgA[2 * tid + 1];
        float4 a2 = fgA[2 * (tid + 256)]; float4 a3 = fgA[2 * (tid + 256) + 1];
        float4 b0 = fgB[2 * tid];         float4 b1 = fgB[2 * tid + 1];
        float4 b2 = fgB[2 * (tid + 256)]; float4 b3 = fgB[2 * (tid + 256) + 1];
        float4 a4, a5, b4, b5;
        if (tid < 44) {
            a4 = fgA[2 * (tid + 512)]; a5 = fgA[2 * (tid + 512) + 1];
            b4 = fgB[2 * (tid + 512)]; b5 = fgB[2 * (tid + 512) + 1];
        }
        *(short8*)(fxA + 8 + 8 * tid)         = pack8(a0, a1);
        *(short8*)(fxA + 8 + 8 * (tid + 256)) = pack8(a2, a3);
        *(short8*)(fxB + 8 + 8 * tid)         = pack8(b0, b1);
        *(short8*)(fxB + 8 + 8 * (tid + 256)) = pack8(b2, b3);
        if (tid < 44) {
            *(short8*)(fxA + 8 + 8 * (tid + 512)) = pack8(a4, a5);
            *(short8*)(fxB + 8 + 8 * (tid + 512)) = pack8(b4, b5);
        }
    }
    __syncthreads();

    // ---------------- stage 1: conv1 as MFMA (transposed D) + pool + bn --------
    // (R9-verified) D[j][oc] = X^T[16 j][32 k'] x Wc1^T[32][16 oc]. A/B interleaved.
    {
        const int lane = tid & 63;
        const int wid  = tid >> 6;
        const int col  = lane & 15;
        const int quad = lane >> 4;
        const short* fxA = (const short*)SA;
        const short* fxB = (const short*)SB;
        const short8 wfrag = *(const short8*)((const short*)SA + WC1_EL + col * 32 + quad * 8);
        const float gsc = fabsf(bn1_g[col]) * BN_RSQ;
        const float gbt = bn1_b[col];

        for (int nt = wid; nt < 70; nt += 4) {
            const int jl = nt * 16 + col;          // A's m-row = conv position
            FragU xuA, xuB;
            xuA.h[0] = *(const short4v*)(fxA + 4 * jl + quad * 8);
            xuA.h[1] = *(const short4v*)(fxA + 4 * jl + quad * 8 + 4);
            xuB.h[0] = *(const short4v*)(fxB + 4 * jl + quad * 8);
            xuB.h[1] = *(const short4v*)(fxB + 4 * jl + quad * 8 + 4);
            f32x4 accA = {0.f, 0.f, 0.f, 0.f};
            f32x4 accB = {0.f, 0.f, 0.f, 0.f};
            accA = __builtin_amdgcn_mfma_f32_16x16x32_bf16(xuA.v, wfrag, accA, 0, 0, 0);
            accB = __builtin_amdgcn_mfma_f32_16x16x32_bf16(xuB.v, wfrag, accB, 0, 0, 0);
            const float mA = fmaxf(fmaxf(accA[0], accA[1]), fmaxf(accA[2], accA[3]));
            const float mB = fmaxf(fmaxf(accB[0], accB[1]), fmaxf(accB[2], accB[3]));
            const int p = nt * 4 + quad;           // pooled position
            if (p < L1P) {
                *((short*)SA + H1T_EL + (4 + p) * 20 + col) =
                    f2bf(fmaxf(mA * gsc + gbt, 0.0f));
                *((short*)SB + H1T_EL + (4 + p) * 20 + col) =
                    f2bf(fmaxf(mB * gsc + gbt, 0.0f));
            }
        }
    }
    __syncthreads();   // h1T_A/B complete; fxb_A/B now dead

    // Wb[oc][K'=k*16+ic] bf16, row stride 136 (k==7 row zero) -> dead fxb_A.
    {
        const int oc = tid >> 3;
        const int k  = tid & 7;
        short8* dst = (short8*)((char*)SA + (WB_EL + oc * 136 + k * 16) * 2);
        dst[0] = wbp0; dst[1] = wbp1;
    }
    __syncthreads();   // Wb ready; featU_A/B still pure pool sums

    // ---------------- stage 2: conv2 as MFMA + bn/relu + pool (A/B interleaved) -
    // (R9/R12-verified) D[j][oc] = X^T[144 j][128] x Wb^T[128][32 oc].
    {
        const int lane = tid & 63;
        const int wid  = tid >> 6;
        const int col  = lane & 15;
        const int quad = lane >> 4;
        const short* h1sA = (const short*)SA + H1T_EL;
        const short* h1sB = (const short*)SB + H1T_EL;
        const char*  wbc  = (const char*)((const short*)SA + WB_EL);
        const float sc0 = bn2_g[col] * BN_RSQ,      bt0 = bn2_b[col];
        const float sc1 = bn2_g[col + 16] * BN_RSQ, bt1 = bn2_b[col + 16];

        short8 wa0[4], wa1[4];
        #pragma unroll
        for (int kb = 0; kb < 4; ++kb) {
            wa0[kb] = *(const short8*)(wbc + (col * 136        + kb*32 + quad*8) * 2);
            wa1[kb] = *(const short8*)(wbc + ((16 + col) * 136 + kb*32 + quad*8) * 2);
        }

        for (int nt = wid; nt < 9; nt += 4) {
            const int n0 = nt * 16;
            f32x4 accA0 = {0.f,0.f,0.f,0.f}, accA1 = {0.f,0.f,0.f,0.f};
            f32x4 accB0 = {0.f,0.f,0.f,0.f}, accB1 = {0.f,0.f,0.f,0.f};
            #pragma unroll
            for (int kb = 0; kb < 4; ++kb) {
                const int k   = 2 * kb + (quad >> 1);
                const int ic0 = (quad & 1) * 8;
                const int row = 2 * (n0 + col) + 1 + k;
                FragU buA, buB;
                buA.h[0] = *(const short4v*)(h1sA + row * 20 + ic0);
                buA.h[1] = *(const short4v*)(h1sA + row * 20 + ic0 + 4);
                buB.h[0] = *(const short4v*)(h1sB + row * 20 + ic0);
                buB.h[1] = *(const short4v*)(h1sB + row * 20 + ic0 + 4);
                accA0 = __builtin_amdgcn_mfma_f32_16x16x32_bf16(buA.v, wa0[kb], accA0, 0, 0, 0);
                accA1 = __builtin_amdgcn_mfma_f32_16x16x32_bf16(buA.v, wa1[kb], accA1, 0, 0, 0);
                accB0 = __builtin_amdgcn_mfma_f32_16x16x32_bf16(buB.v, wa0[kb], accB0, 0, 0, 0);
                accB1 = __builtin_amdgcn_mfma_f32_16x16x32_bf16(buB.v, wa1[kb], accB1, 0, 0, 0);
            }
            const int   bk  = (8 * n0) / 139;
            const int   sBd = (139 * (bk + 1)) >> 3;      // j<=sBd -> bk; j>=sBd -> bk+1
            const float rc0 = (bk == 2 || bk == 5) ? (1.0f/19.0f) : (1.0f/18.0f);
            const float rc1 = (bk == 1 || bk == 4) ? (1.0f/19.0f) : (1.0f/18.0f);
            float vaA0 = 0.f, vbA0 = 0.f, vaA1 = 0.f, vbA1 = 0.f;
            float vaB0 = 0.f, vbB0 = 0.f, vaB1 = 0.f, vbB1 = 0.f;
            #pragma unroll
            for (int r = 0; r < 4; ++r) {
                const int j = n0 + quad * 4 + r;
                float vA0 = fmaxf(accA0[r] * sc0 + bt0, 0.0f);
                float vA1 = fmaxf(accA1[r] * sc1 + bt1, 0.0f);
                float vB0 = fmaxf(accB0[r] * sc0 + bt0, 0.0f);
                float vB1 = fmaxf(accB1[r] * sc1 + bt1, 0.0f);
                if (j > 138) { vA0 = 0.0f; vA1 = 0.0f; vB0 = 0.0f; vB1 = 0.0f; }
                if (j <= sBd) { vaA0 += vA0; vaA1 += vA1; vaB0 += vB0; vaB1 += vB1; }
                if (j >= sBd) { vbA0 += vA0; vbA1 += vA1; vbB0 += vB0; vbB1 += vB1; }
            }
            vaA0 += __shfl_xor(vaA0, 16, 64); vaA0 += __shfl_xor(vaA0, 32, 64);
            vaA1 += __shfl_xor(vaA1, 16, 64); vaA1 += __shfl_xor(vaA1, 32, 64);
            vbA0 += __shfl_xor(vbA0, 16, 64); vbA0 += __shfl_xor(vbA0, 32, 64);
            vbA1 += __shfl_xor(vbA1, 16, 64); vbA1 += __shfl_xor(vbA1, 32, 64);
            vaB0 += __shfl_xor(vaB0, 16, 64); vaB0 += __shfl_xor(vaB0, 32, 64);
            vaB1 += __shfl_xor(vaB1, 16, 64); vaB1 += __shfl_xor(vaB1, 32, 64);
            vbB0 += __shfl_xor(vbB0, 16, 64); vbB0 += __shfl_xor(vbB0, 32, 64);
            vbB1 += __shfl_xor(vbB1, 16, 64); vbB1 += __shfl_xor(vbB1, 32, 64);
            if (quad == 0) {
                atomicAdd(&featUA[col * 8 + bk],        vaA0 * rc0);
                atomicAdd(&featUA[(col + 16) * 8 + bk], vaA1 * rc0);
                atomicAdd(&featUB[col * 8 + bk],        vaB0 * rc0);
                atomicAdd(&featUB[(col + 16) * 8 + bk], vaB1 * rc0);
                if (bk < 7) {
                    atomicAdd(&featUA[col * 8 + bk + 1],        vbA0 * rc1);
                    atomicAdd(&featUA[(col + 16) * 8 + bk + 1], vbA1 * rc1);
                    atomicAdd(&featUB[col * 8 + bk + 1],        vbB0 * rc1);
                    atomicAdd(&featUB[(col + 16) * 8 + bk + 1], vbB1 * rc1);
                }
            }
        }
    }
    __syncthreads();

    // ---------------- proj1 (256 -> 64), relu — shared weights, 2 dots --------
    {
        const int o = tid >> 2, s = tid & 3;
        const float4* wg  = (const float4*)(proj_w1 + 64 * tid);   // == o*256 + s*64
        const float4* xfA = (const float4*)(featUA + 64 * s);
        const float4* xfB = (const float4*)(featUB + 64 * s);
        float accA = 0.0f, accB = 0.0f;
        #pragma unroll
        for (int t = 0; t < 16; ++t) {
            float4 w4 = wg[t], a4 = xfA[t], b4 = xfB[t];
            accA += w4.x * a4.x + w4.y * a4.y + w4.z * a4.z + w4.w * a4.w;
            accB += w4.x * b4.x + w4.y * b4.y + w4.z * b4.z + w4.w * b4.w;
        }
        accA += __shfl_down(accA, 2, 64); accB += __shfl_down(accB, 2, 64);
        accA += __shfl_down(accA, 1, 64); accB += __shfl_down(accB, 1, 64);
        if (s == 0) {
            s_hiddenA[o] = fmaxf(accA + proj_b1[o], 0.0f);
            s_hiddenB[o] = fmaxf(accB + proj_b1[o], 0.0f);
        }
    }
    __syncthreads();

    // gate matrices into featUA alias (SHARED; published by norm barrier below)
    if (tid < NL * NQ) {
        float phi = qw[tid * 3 + 0], th = qw[tid * 3 + 1], om = qw[tid * 3 + 2];
        float ch = cosf(0.5f * th), sh = sinf(0.5f * th);
        float a  = 0.5f * (phi + om), bb = 0.5f * (phi - om);
        float ca = cosf(a), sa = sinf(a), cb = cosf(bb), sb = sinf(bb);
        float* U = &s_U[tid * 8];
        U[0] =  ca * ch; U[1] = -sa * ch;   // U00
        U[2] = -cb * sh; U[3] = -sb * sh;   // U01
        U[4] =  cb * sh; U[5] = -sb * sh;   // U10
        U[6] =  ca * ch; U[7] =  sa * ch;   // U11
    }

    // ---------------- proj2 (64 -> 256) + L2 normalize (A/B interleaved) ------
    float reA, reB;
    {
        const float4* wg  = (const float4*)(proj_w2 + 64 * tid);
        const float4* hfA = (const float4*)s_hiddenA;
        const float4* hfB = (const float4*)s_hiddenB;
        float accA = proj_b2[tid], accB = accA;
        #pragma unroll
        for (int t = 0; t < 16; ++t) {
            float4 w4 = wg[t], a4 = hfA[t], b4 = hfB[t];
            accA += w4.x * a4.x + w4.y * a4.y + w4.z * a4.z + w4.w * a4.w;
            accB += w4.x * b4.x + w4.y * b4.y + w4.z * b4.z + w4.w * b4.w;
        }
        float ssA = accA * accA, ssB = accB * accB;
        #pragma unroll
        for (int off = 32; off >= 1; off >>= 1) {
            ssA += __shfl_xor(ssA, off, 64);
            ssB += __shfl_xor(ssB, off, 64);
        }
        if ((tid & 63) == 0) { s_redA[tid >> 6] = ssA; s_redB[tid >> 6] = ssB; }
        __syncthreads();                           // also publishes s_U
        float sstA = s_redA[0] + s_redA[1] + s_redA[2] + s_redA[3];
        float sstB = s_redB[0] + s_redB[1] + s_redB[2] + s_redB[3];
        float nA = sqrtf(sstA), nB = sqrtf(sstB);
        float invA = 1.0f / fmaxf(nA, 1e-12f);
        float invB = 1.0f / fmaxf(nB, 1e-12f);
        float xiA = accA * invA, xiB = accB * invB;
        if (nA * invA < 1e-8f) xiA = 0.0625f;      // uniform 1/sqrt(256)
        if (nB * invB < 1e-8f) xiB = 0.0625f;
        reA = xiA; reB = xiB;                      // initial state real (im = 0)
    }

    // ---------------- R15/R16 tail: 4-wave circuit, A/B interleaved -----------
    float2* ampcA = (float2*)(SA + 256);
    float2* ampcB = (float2*)(SB + 256);
    float*  wpA   = SA + 64;             // Walsh parts [4][7]
    float*  wpB   = SB + 64;

    const int lane = tid & 63;
    const int w    = tid >> 6;
    const int b7   = w >> 1, b6 = w & 1;
    const int sl   = permsrc(lane);                      // may set bits 6,7
    const int pw   = (b6 ? P40 : 0) ^ (b7 ? P80 : 0);    // permsrc(w<<6)

    ampcA[tid] = make_float2(reA, 0.0f);
    ampcB[tid] = make_float2(reB, 0.0f);
    __syncthreads();           // amps + s_U visible to all waves

    float arA = 0.0f, aiA = 0.0f, arB = 0.0f, aiB = 0.0f;
    #pragma unroll
    for (int l = 0; l < NL; ++l) {
        // --- exchange + combined q=0 (bit7), q=1 (bit6) gates ---
        float oAr[4], oAi[4], oBr[4], oBi[4];
        #pragma unroll
        for (int j = 0; j < 4; ++j) {
            const int src = (l == 0) ? (lane + 64 * j)
                                     : (sl ^ ((j & 1 ? P40 : 0) ^ (j & 2 ? P80 : 0)));
            const float2 vA = ampcA[src];
            const float2 vB = ampcB[src];
            oAr[j] = vA.x; oAi[j] = (l == 0) ? 0.0f : vA.y;
            oBr[j] = vB.x; oBi[j] = (l == 0) ? 0.0f : vB.y;
        }
        {
            const float* U0 = &s_U[(l * NQ + 0) * 8];
            const float* U1 = &s_U[(l * NQ + 1) * 8];
            const float a0r = b7 ? U0[4] : U0[0], a0i = b7 ? U0[5] : U0[1];
            const float a1r = b7 ? U0[6] : U0[2], a1i = b7 ? U0[7] : U0[3];
            const float c0r = b6 ? U1[4] : U1[0], c0i = b6 ? U1[5] : U1[1];
            const float c1r = b6 ? U1[6] : U1[2], c1i = b6 ? U1[7] : U1[3];
            // A
            const float tA0r = a0r*oAr[0] - a0i*oAi[0] + a1r*oAr[2] - a1i*oAi[2];
            const float tA0i = a0r*oAi[0] + a0i*oAr[0] + a1r*oAi[2] + a1i*oAr[2];
            const float tA1r = a0r*oAr[1] - a0i*oAi[1] + a1r*oAr[3] - a1i*oAi[3];
            const float tA1i = a0r*oAi[1] + a0i*oAr[1] + a1r*oAi[3] + a1i*oAr[3];
            arA = c0r*tA0r - c0i*tA0i + c1r*tA1r - c1i*tA1i;
            aiA = c0r*tA0i + c0i*tA0r + c1r*tA1i + c1i*tA1r;
            // B
            const float tB0r = a0r*oBr[0] - a0i*oBi[0] + a1r*oBr[2] - a1i*oBi[2];
            const float tB0i = a0r*oBi[0] + a0i*oBr[0] + a1r*oBi[2] + a1i*oBr[2];
            const float tB1r = a0r*oBr[1] - a0i*oBi[1] + a1r*oBr[3] - a1i*oBi[3];
            const float tB1i = a0r*oBi[1] + a0i*oBr[1] + a1r*oBi[3] + a1i*oBr[3];
            arB = c0r*tB0r - c0i*tB0i + c1r*tB1r - c1i*tB1i;
            aiB = c0r*tB0i + c0i*tB0r + c1r*tB1i + c1i*tB1r;
        }
        // --- q=2..7: lane-bit gates via shuffles, A/B chains interleaved ---
        #pragma unroll
        for (int q = 2; q < NQ; ++q) {
            const float* U = &s_U[(l * NQ + q) * 8];
            const int bp  = 7 - q;
            const int bit = (lane >> bp) & 1;
            const float csr = bit ? U[6] : U[0];
            const float csi = bit ? U[7] : U[1];
            const float cpr = bit ? U[4] : U[2];
            const float cpi = bit ? U[5] : U[3];
            const float pAr = __shfl_xor(arA, 1 << bp, 64);
            const float pAi = __shfl_xor(aiA, 1 << bp, 64);
            const float pBr = __shfl_xor(arB, 1 << bp, 64);
            const float pBi = __shfl_xor(aiB, 1 << bp, 64);
            const float nAr = csr * arA - csi * aiA + cpr * pAr - cpi * pAi;
            const float nAi = csr * aiA + csi * arA + cpr * pAi + cpi * pAr;
            const float nBr = csr * arB - csi * aiB + cpr * pBr - cpi * pBi;
            const float nBi = csr * aiB + csi * arB + cpr * pBi + cpi * pBr;
            arA = nAr; aiA = nAi; arB = nBr; aiB = nBi;
        }
        __syncthreads();                 // all reads of ampc done before overwrite
        ampcA[tid] = make_float2(arA, aiA);
        ampcB[tid] = make_float2(arB, aiB);
        __syncthreads();                 // writes visible for next read
    }

    // final CNOT-ring of layer 3: read own permuted amp
    {
        const float2 vA = ampcA[sl ^ pw];
        const float2 vB = ampcB[sl ^ pw];
        arA = vA.x; aiA = vA.y; arB = vB.x; aiB = vB.y;
    }

    // Walsh-Hadamard: per-wave signed butterfly (R10-verified), A/B interleaved
    {
        const float pA = arA * arA + aiA * aiA;
        const float pB = arB * arB + aiB * aiB;
        float tA = pA, tB = pB;
        #pragma unroll
        for (int d = 0; d < 6; ++d) {
            const float sAs = __shfl_xor(tA, 1 << d, 64);
            const float sBs = __shfl_xor(tB, 1 << d, 64);
            tA = ((lane >> d) & 1) ? (sAs - tA) : (tA + sAs);
            tB = ((lane >> d) & 1) ? (sBs - tB) : (tB + sBs);
        }
        if (lane == 0) { wpA[w * 7] = tA; wpB[w * 7] = tB; }
        else if ((lane & (lane - 1)) == 0) {
            const int d = 31 - __clz(lane);                 // lane = 1<<d, d 0..5
            wpA[w * 7 + 1 + d] = tA;                        // qubit 7-d partial
            wpB[w * 7 + 1 + d] = tB;
        }
    }
    __syncthreads();           // wp visible; waves 2-3 exit after this

    // wave 0 -> sample A, wave 1 -> sample B (independent heads in parallel)
    if (tid < 128) {
        const int sm = tid >> 6;
        const float* wpp = sm ? wpB : wpA;
        float* sq        = sm ? s_qB : s_qA;
        const int bb     = sm ? iB : iA;
        // combine Walsh parts -> s_q (same-wave LDS, program-ordered)
        if (lane < 8) {
            float v;
            if (lane == 0)      v = wpp[0] + wpp[7] - wpp[14] - wpp[21];   // bit7
            else if (lane == 1) v = wpp[0] - wpp[7] + wpp[14] - wpp[21];   // bit6
            else {
                const int d = 7 - lane;                                     // q=2..7
                v = wpp[1 + d] + wpp[8 + d] + wpp[15 + d] + wpp[22 + d];
            }
            sq[lane] = v;
        }
        // head layer 1 (lanes 0..31; sq read-after-write, same wave)
        float h = 0.0f;
        if (lane < 32) {
            float acc = head_b1[lane];
            #pragma unroll
            for (int k = 0; k < 8; ++k) acc += head_w1[lane * 14 + k] * sq[k];
            #pragma unroll
            for (int k = 0; k < 6; ++k) acc += head_w1[lane * 14 + 8 + k] * scalars[bb * 6 + k];
            h = fmaxf(acc * (head_bn_g[lane] * BN_RSQ) + head_bn_b[lane], 0.0f);
        }
        // head layer 2: 3 dot-products over 32 h values via butterfly reduce
        float p0 = (lane < 32) ? h * head_w2[lane]      : 0.0f;
        float p1 = (lane < 32) ? h * head_w2[32 + lane] : 0.0f;
        float p2 = (lane < 32) ? h * head_w2[64 + lane] : 0.0f;
        #pragma unroll
        for (int d = 0; d < 6; ++d) {
            p0 += __shfl_xor(p0, 1 << d, 64);
            p1 += __shfl_xor(p1, 1 << d, 64);
            p2 += __shfl_xor(p2, 1 << d, 64);
        }
        if (lane < 3) {
            const float v = (lane == 0) ? p0 : ((lane == 1) ? p1 : p2);
            out[bb * 3 + lane] = v + head_b2[lane];
        }
    }
}

extern "C" void kernel_launch(void* const* d_in, const int* in_sizes, int n_in,
                              void* d_out, int out_size, void* d_ws, size_t ws_size,
                              hipStream_t stream) {
    const float* flux      = (const float*)d_in[0];
    const float* scalars   = (const float*)d_in[1];
    const float* conv1_w   = (const float*)d_in[2];
    const float* bn1_g     = (const float*)d_in[3];
    const float* bn1_b     = (const float*)d_in[4];
    const float* conv2_w   = (const float*)d_in[5];
    const float* bn2_g     = (const float*)d_in[6];
    const float* bn2_b     = (const float*)d_in[7];
    const float* proj_w1   = (const float*)d_in[8];
    const float* proj_b1   = (const float*)d_in[9];
    const float* proj_w2   = (const float*)d_in[10];
    const float* proj_b2   = (const float*)d_in[11];
    const float* q_weights = (const float*)d_in[12];
    const float* head_w1   = (const float*)d_in[13];
    const float* head_b1   = (const float*)d_in[14];
    const float* head_bn_g = (const float*)d_in[15];
    const float* head_bn_b = (const float*)d_in[16];
    const float* head_w2   = (const float*)d_in[17];
    const float* head_b2   = (const float*)d_in[18];

    const int B = in_sizes[0] / L0;   // 4096

    aec_fused_kernel<<<dim3(B / 2), dim3(256), 0, stream>>>(
        flux, scalars, conv1_w, bn1_g, bn1_b, conv2_w, bn2_g, bn2_b,
        proj_w1, proj_b1, proj_w2, proj_b2, q_weights,
        head_w1, head_b1, head_bn_g, head_bn_b, head_w2, head_b2,
        (float*)d_out);
}